// Round 1
// baseline (4859.306 us; speedup 1.0000x reference)
//
#include <hip/hip_runtime.h>
#include <math.h>

#define NN 50000
#define NE 800000
#define FD 128
#define NG 64
#define NCLS_ 10
#define EPS_BN 1e-5f
#define SLOPE 0.2f

// ---------------- GEMM: h = x @ W  (x: [NN,128], W: [128,128]) ----------------
__global__ __launch_bounds__(256) void gemm_xw(const float* __restrict__ x,
                                               const float* __restrict__ W,
                                               float* __restrict__ h, int nrows) {
  __shared__ float Wl[FD * FD];       // 64 KB
  __shared__ float xl[2][FD];
  for (int i = threadIdx.x; i < FD * FD / 4; i += 256)
    reinterpret_cast<float4*>(Wl)[i] = reinterpret_cast<const float4*>(W)[i];
  __syncthreads();
  const int col = threadIdx.x & 127;
  const int r = threadIdx.x >> 7;     // 0..1
  for (int base = blockIdx.x * 2; base < nrows; base += gridDim.x * 2) {
    const int n = base + r;
    __syncthreads();                  // protect xl from previous iteration readers
    if (n < nrows) xl[r][col] = x[(size_t)n * FD + col];
    __syncthreads();
    if (n < nrows) {
      float acc = 0.f;
      #pragma unroll
      for (int k = 0; k < FD; ++k)
        acc = fmaf(xl[r][k], Wl[k * FD + col], acc);
      h[(size_t)n * FD + col] = acc;
    }
  }
}

// ------------- per-node attention logits + self-loop weight / denom init -------------
template <int H, int C>
__global__ __launch_bounds__(256) void al_node(const float* __restrict__ h,
                                               const float* __restrict__ as_,
                                               const float* __restrict__ ad_,
                                               float* __restrict__ als,
                                               float* __restrict__ ald,
                                               float* __restrict__ wself,
                                               float* __restrict__ denom) {
  int t = blockIdx.x * 256 + threadIdx.x;
  if (t >= NN * H) return;
  int n = t / H, hh = t % H;
  const float* hp = h + (size_t)n * FD + hh * C;
  float ss = 0.f, dd = 0.f;
  #pragma unroll
  for (int c = 0; c < C; ++c) {
    float v = hp[c];
    ss = fmaf(v, as_[hh * C + c], ss);
    dd = fmaf(v, ad_[hh * C + c], dd);
  }
  als[t] = ss;
  ald[t] = dd;
  float a = ss + dd;
  a = a > 0.f ? a : SLOPE * a;
  float w = expf(a);                 // self-loop edge weight (softmax shift skipped: invariant)
  wself[t] = w;
  denom[t] = w;                      // init denom with self-loop contribution
}

// ---------------- per-edge: exp weights + denom accumulation ----------------
template <int H>
__global__ __launch_bounds__(256) void edge_denom(const int* __restrict__ src,
                                                  const int* __restrict__ dst,
                                                  const float* __restrict__ als,
                                                  const float* __restrict__ ald,
                                                  float* __restrict__ ew,
                                                  float* __restrict__ denom) {
  int e = blockIdx.x * 256 + threadIdx.x;
  if (e >= NE) return;
  int s = src[e], d = dst[e];
  #pragma unroll
  for (int hh = 0; hh < H; ++hh) {
    float a = als[s * H + hh] + ald[d * H + hh];
    a = a > 0.f ? a : SLOPE * a;
    float w = expf(a);
    ew[(size_t)e * H + hh] = w;
    atomicAdd(&denom[d * H + hh], w);
  }
}

// ---------------- out init with self-loop message ----------------
template <int H, int C>
__global__ __launch_bounds__(256) void out_init(const float* __restrict__ h,
                                                const float* __restrict__ wself,
                                                const float* __restrict__ denom,
                                                float* __restrict__ out) {
  int t = blockIdx.x * 256 + threadIdx.x;
  if (t >= NN * FD) return;
  int n = t >> 7, j = t & 127;
  int hh = j / C;
  float coef = wself[n * H + hh] / denom[n * H + hh];
  out[t] = coef * h[t];
}

// ---------------- per-edge message scatter (32 lanes / edge) ----------------
template <int H, int C>
__global__ __launch_bounds__(256) void edge_msg(const int* __restrict__ src,
                                                const int* __restrict__ dst,
                                                const float* __restrict__ h,
                                                const float* __restrict__ ew,
                                                const float* __restrict__ denom,
                                                float* __restrict__ out) {
  int t = blockIdx.x * 256 + threadIdx.x;
  int e = t >> 5;
  if (e >= NE) return;
  int lane = t & 31;
  int j0 = lane * 4;
  int s = src[e], d = dst[e];
  int hh = j0 / C;
  float coef = ew[(size_t)e * H + hh] / denom[d * H + hh];
  const float4 hv = *reinterpret_cast<const float4*>(h + (size_t)s * FD + j0);
  float* op = out + (size_t)d * FD + j0;
  atomicAdd(op + 0, coef * hv.x);
  atomicAdd(op + 1, coef * hv.y);
  atomicAdd(op + 2, coef * hv.z);
  atomicAdd(op + 3, coef * hv.w);
}

// ---------------- bias + BN(eval) + ReLU ----------------
__global__ __launch_bounds__(256) void post_bn_relu(const float* __restrict__ out,
                                                    const float* __restrict__ b,
                                                    const float* __restrict__ g,
                                                    const float* __restrict__ bb,
                                                    const float* __restrict__ rm,
                                                    const float* __restrict__ rv,
                                                    float* __restrict__ xnext) {
  int t = blockIdx.x * 256 + threadIdx.x;
  if (t >= NN * FD) return;
  int j = t & 127;
  float v = out[t] + b[j];
  v = g[j] * (v - rm[j]) * rsqrtf(rv[j] + EPS_BN) + bb[j];
  xnext[t] = v > 0.f ? v : 0.f;
}

// ---------------- pooled zero init ----------------
__global__ __launch_bounds__(256) void pool_zero(float* __restrict__ pooled) {
  int t = blockIdx.x * 256 + threadIdx.x;
  if (t < NG * FD) pooled[t] = 0.f;
}

// ---------------- global add pool (batch is sorted) ----------------
__global__ __launch_bounds__(128) void pool_sum(const float* __restrict__ x,
                                                const int* __restrict__ batch,
                                                float* __restrict__ pooled) {
  int j = threadIdx.x;                 // 0..127
  int base = blockIdx.x * 256;
  if (base >= NN) return;
  int end = base + 256;
  if (end > NN) end = NN;
  float acc = 0.f;
  int cur = batch[base];
  for (int n = base; n < end; ++n) {
    int g = batch[n];
    if (g != cur) {
      atomicAdd(&pooled[cur * FD + j], acc);
      acc = 0.f;
      cur = g;
    }
    acc += x[(size_t)n * FD + j];
  }
  atomicAdd(&pooled[cur * FD + j], acc);
}

// ---------------- classifier: [64,128] @ [128,10] + bc ----------------
__global__ __launch_bounds__(640) void cls_kernel(const float* __restrict__ pooled,
                                                  const float* __restrict__ Wc,
                                                  const float* __restrict__ bc,
                                                  float* __restrict__ out) {
  int t = threadIdx.x;
  if (t >= NG * NCLS_) return;
  int g = t / NCLS_, k = t % NCLS_;
  float acc = bc[k];
  #pragma unroll 16
  for (int j = 0; j < FD; ++j)
    acc = fmaf(pooled[g * FD + j], Wc[j * NCLS_ + k], acc);
  out[t] = acc;
}

extern "C" void kernel_launch(void* const* d_in, const int* in_sizes, int n_in,
                              void* d_out, int out_size, void* d_ws, size_t ws_size,
                              hipStream_t stream) {
  const float* x = (const float*)d_in[0];
  const int* ei = (const int*)d_in[1];
  const int* batch = (const int*)d_in[2];
  const int* src = ei;
  const int* dst = ei + NE;
  const float* W[3]  = {(const float*)d_in[3],  (const float*)d_in[11], (const float*)d_in[19]};
  const float* AS[3] = {(const float*)d_in[4],  (const float*)d_in[12], (const float*)d_in[20]};
  const float* AD[3] = {(const float*)d_in[5],  (const float*)d_in[13], (const float*)d_in[21]};
  const float* B[3]  = {(const float*)d_in[6],  (const float*)d_in[14], (const float*)d_in[22]};
  const float* Gm[3] = {(const float*)d_in[7],  (const float*)d_in[15], (const float*)d_in[23]};
  const float* BB[3] = {(const float*)d_in[8],  (const float*)d_in[16], (const float*)d_in[24]};
  const float* RM[3] = {(const float*)d_in[9],  (const float*)d_in[17], (const float*)d_in[25]};
  const float* RV[3] = {(const float*)d_in[10], (const float*)d_in[18], (const float*)d_in[26]};
  const float* Wc = (const float*)d_in[27];
  const float* bc = (const float*)d_in[28];

  float* ws = (float*)d_ws;
  float* h      = ws;
  float* outb   = h + (size_t)NN * FD;
  float* xcur   = outb + (size_t)NN * FD;
  float* als    = xcur + (size_t)NN * FD;
  float* ald    = als + (size_t)NN * 4;
  float* wse    = ald + (size_t)NN * 4;
  float* den    = wse + (size_t)NN * 4;
  float* ew     = den + (size_t)NN * 4;
  float* pooled = ew + (size_t)NE * 4;

  for (int layer = 0; layer < 3; ++layer) {
    const float* xin = (layer == 0) ? x : xcur;
    gemm_xw<<<512, 256, 0, stream>>>(xin, W[layer], h, NN);
    if (layer < 2) {
      al_node<4, 32><<<(NN * 4 + 255) / 256, 256, 0, stream>>>(h, AS[layer], AD[layer], als, ald, wse, den);
      edge_denom<4><<<(NE + 255) / 256, 256, 0, stream>>>(src, dst, als, ald, ew, den);
      out_init<4, 32><<<(NN * FD + 255) / 256, 256, 0, stream>>>(h, wse, den, outb);
      edge_msg<4, 32><<<((size_t)NE * 32 + 255) / 256, 256, 0, stream>>>(src, dst, h, ew, den, outb);
    } else {
      al_node<1, 128><<<(NN + 255) / 256, 256, 0, stream>>>(h, AS[2], AD[2], als, ald, wse, den);
      edge_denom<1><<<(NE + 255) / 256, 256, 0, stream>>>(src, dst, als, ald, ew, den);
      out_init<1, 128><<<(NN * FD + 255) / 256, 256, 0, stream>>>(h, wse, den, outb);
      edge_msg<1, 128><<<((size_t)NE * 32 + 255) / 256, 256, 0, stream>>>(src, dst, h, ew, den, outb);
    }
    post_bn_relu<<<(NN * FD + 255) / 256, 256, 0, stream>>>(outb, B[layer], Gm[layer], BB[layer],
                                                            RM[layer], RV[layer], xcur);
  }
  pool_zero<<<(NG * FD + 255) / 256, 256, 0, stream>>>(pooled);
  pool_sum<<<(NN + 255) / 256, 128, 0, stream>>>(xcur, batch, pooled);
  cls_kernel<<<1, 640, 0, stream>>>(pooled, Wc, bc, (float*)d_out);
}

// Round 2
// 685.650 us; speedup vs baseline: 7.0871x; 7.0871x over previous
//
#include <hip/hip_runtime.h>
#include <math.h>

#define NN 50000
#define NE 800000
#define FD 128
#define NG 64
#define NCLS_ 10
#define EPS_BN 1e-5f
#define SLOPE 0.2f

__device__ __forceinline__ float lrelu(float a) { return a > 0.f ? a : SLOPE * a; }

// ---------------- GEMM: h = x @ W  (x: [NN,128], W: [128,128]) ----------------
// Block tile: 32 rows x 128 cols, K-tiled by 32. Thread: 4 rows x 4 cols.
__global__ __launch_bounds__(256) void gemm_xw(const float* __restrict__ x,
                                               const float* __restrict__ W,
                                               float* __restrict__ h) {
  __shared__ float Wl[32][128];   // 16 KB
  __shared__ float xl[32][32];    // 4 KB
  const int t = threadIdx.x;
  const int cgrp = t & 31;        // 32 col groups
  const int rgrp = t >> 5;        // 8 row groups
  const int c0 = cgrp * 4;
  const int r0 = rgrp * 4;
  const int base = blockIdx.x * 32;

  float acc[4][4];
  #pragma unroll
  for (int i = 0; i < 4; ++i)
    #pragma unroll
    for (int j = 0; j < 4; ++j) acc[i][j] = 0.f;

  for (int kt = 0; kt < 4; ++kt) {
    __syncthreads();
    // load W tile: 4096 floats = 1024 float4, 4 per thread
    #pragma unroll
    for (int i = 0; i < 4; ++i) {
      int idx = t + 256 * i;
      int kr = idx >> 5, c4 = (idx & 31) * 4;
      *reinterpret_cast<float4*>(&Wl[kr][c4]) =
          *reinterpret_cast<const float4*>(&W[(kt * 32 + kr) * FD + c4]);
    }
    // load x tile: 1024 floats = 256 float4, 1 per thread
    {
      int r = t >> 3, k4 = (t & 7) * 4;
      int n = base + r;
      float4 v = make_float4(0.f, 0.f, 0.f, 0.f);
      if (n < NN) v = *reinterpret_cast<const float4*>(&x[(size_t)n * FD + kt * 32 + k4]);
      *reinterpret_cast<float4*>(&xl[r][k4]) = v;
    }
    __syncthreads();
    #pragma unroll
    for (int kk = 0; kk < 32; ++kk) {
      float4 wv = *reinterpret_cast<const float4*>(&Wl[kk][c0]);
      #pragma unroll
      for (int i = 0; i < 4; ++i) {
        float xv = xl[r0 + i][kk];
        acc[i][0] = fmaf(xv, wv.x, acc[i][0]);
        acc[i][1] = fmaf(xv, wv.y, acc[i][1]);
        acc[i][2] = fmaf(xv, wv.z, acc[i][2]);
        acc[i][3] = fmaf(xv, wv.w, acc[i][3]);
      }
    }
  }
  #pragma unroll
  for (int i = 0; i < 4; ++i) {
    int n = base + r0 + i;
    if (n < NN)
      *reinterpret_cast<float4*>(&h[(size_t)n * FD + c0]) =
          make_float4(acc[i][0], acc[i][1], acc[i][2], acc[i][3]);
  }
}

// ------------- per-node attention logits -------------
template <int H, int C>
__global__ __launch_bounds__(256) void al_node(const float* __restrict__ h,
                                               const float* __restrict__ as_,
                                               const float* __restrict__ ad_,
                                               float* __restrict__ als,
                                               float* __restrict__ ald) {
  int t = blockIdx.x * 256 + threadIdx.x;
  if (t >= NN * H) return;
  int n = t / H, hh = t % H;
  const float* hp = h + (size_t)n * FD + hh * C;
  float ss = 0.f, dd = 0.f;
  #pragma unroll
  for (int c = 0; c < C; ++c) {
    float v = hp[c];
    ss = fmaf(v, as_[hh * C + c], ss);
    dd = fmaf(v, ad_[hh * C + c], dd);
  }
  als[t] = ss;
  ald[t] = dd;
}

// ---------------- CSR build ----------------
__global__ __launch_bounds__(256) void zero_cnt(int* __restrict__ cnt) {
  int t = blockIdx.x * 256 + threadIdx.x;
  if (t < NN) cnt[t] = 0;
}

__global__ __launch_bounds__(256) void hist_dst(const int* __restrict__ dst,
                                                int* __restrict__ cnt) {
  int e = blockIdx.x * 256 + threadIdx.x;
  if (e < NE) atomicAdd(&cnt[dst[e]], 1);
}

__global__ __launch_bounds__(256) void scan_rowptr(const int* __restrict__ cnt,
                                                   int* __restrict__ row_ptr,
                                                   int* __restrict__ cursor) {
  __shared__ int sums[256];
  const int CH = (NN + 255) / 256;  // 196
  int t = threadIdx.x;
  int lo = t * CH, hi = lo + CH;
  if (hi > NN) hi = NN;
  int s = 0;
  for (int i = lo; i < hi; ++i) s += cnt[i];
  sums[t] = s;
  __syncthreads();
  if (t == 0) {
    int run = 0;
    for (int i = 0; i < 256; ++i) { int v = sums[i]; sums[i] = run; run += v; }
    row_ptr[NN] = run;
  }
  __syncthreads();
  int run = sums[t];
  for (int i = lo; i < hi; ++i) {
    row_ptr[i] = run;
    cursor[i] = run;
    run += cnt[i];
  }
}

__global__ __launch_bounds__(256) void scatter_edges(const int* __restrict__ src,
                                                     const int* __restrict__ dst,
                                                     int* __restrict__ cursor,
                                                     int* __restrict__ col) {
  int e = blockIdx.x * 256 + threadIdx.x;
  if (e >= NE) return;
  int pos = atomicAdd(&cursor[dst[e]], 1);
  col[pos] = src[e];
}

// ---------------- fused gather: softmax-weighted aggregation + bias + BN + ReLU ----------------
// One 64-lane wave per dst node; each lane owns 2 channels (float2).
template <int H, int C>
__global__ __launch_bounds__(256) void gat_gather(const int* __restrict__ row_ptr,
                                                  const int* __restrict__ col,
                                                  const float* __restrict__ h,
                                                  const float* __restrict__ als,
                                                  const float* __restrict__ ald,
                                                  const float* __restrict__ b,
                                                  const float* __restrict__ g,
                                                  const float* __restrict__ bb,
                                                  const float* __restrict__ rm,
                                                  const float* __restrict__ rv,
                                                  float* __restrict__ xnext) {
  int wid = (blockIdx.x * 256 + threadIdx.x) >> 6;   // node id
  if (wid >= NN) return;
  const int lane = threadIdx.x & 63;
  const int j0 = lane * 2;
  const int hh = j0 / C;
  const int d = wid;

  const float ald_d = ald[d * H + hh];
  // self-loop
  float w = __expf(lrelu(als[d * H + hh] + ald_d));
  float2 hv = *reinterpret_cast<const float2*>(h + (size_t)d * FD + j0);
  float accx = w * hv.x, accy = w * hv.y;
  float denom = w;

  const int e0 = row_ptr[d], e1 = row_ptr[d + 1];
  for (int e = e0; e < e1; ++e) {
    int s = col[e];
    float w2 = __expf(lrelu(als[s * H + hh] + ald_d));
    float2 hs = *reinterpret_cast<const float2*>(h + (size_t)s * FD + j0);
    accx = fmaf(w2, hs.x, accx);
    accy = fmaf(w2, hs.y, accy);
    denom += w2;
  }
  float inv = 1.f / denom;
  int j = j0;
  float v0 = accx * inv + b[j];
  float v1 = accy * inv + b[j + 1];
  v0 = g[j] * (v0 - rm[j]) * rsqrtf(rv[j] + EPS_BN) + bb[j];
  v1 = g[j + 1] * (v1 - rm[j + 1]) * rsqrtf(rv[j + 1] + EPS_BN) + bb[j + 1];
  v0 = v0 > 0.f ? v0 : 0.f;
  v1 = v1 > 0.f ? v1 : 0.f;
  *reinterpret_cast<float2*>(xnext + (size_t)d * FD + j0) = make_float2(v0, v1);
}

// ---------------- pooling ----------------
__global__ __launch_bounds__(256) void pool_zero(float* __restrict__ pooled) {
  int t = blockIdx.x * 256 + threadIdx.x;
  if (t < NG * FD) pooled[t] = 0.f;
}

__global__ __launch_bounds__(128) void pool_sum(const float* __restrict__ x,
                                                const int* __restrict__ batch,
                                                float* __restrict__ pooled) {
  int j = threadIdx.x;                 // 0..127
  int base = blockIdx.x * 256;
  if (base >= NN) return;
  int end = base + 256;
  if (end > NN) end = NN;
  float acc = 0.f;
  int cur = batch[base];
  for (int n = base; n < end; ++n) {
    int gg = batch[n];
    if (gg != cur) {
      atomicAdd(&pooled[cur * FD + j], acc);
      acc = 0.f;
      cur = gg;
    }
    acc += x[(size_t)n * FD + j];
  }
  atomicAdd(&pooled[cur * FD + j], acc);
}

// ---------------- classifier ----------------
__global__ __launch_bounds__(640) void cls_kernel(const float* __restrict__ pooled,
                                                  const float* __restrict__ Wc,
                                                  const float* __restrict__ bc,
                                                  float* __restrict__ out) {
  int t = threadIdx.x;
  if (t >= NG * NCLS_) return;
  int g = t / NCLS_, k = t % NCLS_;
  float acc = bc[k];
  #pragma unroll 16
  for (int j = 0; j < FD; ++j)
    acc = fmaf(pooled[g * FD + j], Wc[j * NCLS_ + k], acc);
  out[t] = acc;
}

extern "C" void kernel_launch(void* const* d_in, const int* in_sizes, int n_in,
                              void* d_out, int out_size, void* d_ws, size_t ws_size,
                              hipStream_t stream) {
  const float* x = (const float*)d_in[0];
  const int* ei = (const int*)d_in[1];
  const int* batch = (const int*)d_in[2];
  const int* src = ei;
  const int* dst = ei + NE;
  const float* W[3]  = {(const float*)d_in[3],  (const float*)d_in[11], (const float*)d_in[19]};
  const float* AS[3] = {(const float*)d_in[4],  (const float*)d_in[12], (const float*)d_in[20]};
  const float* AD[3] = {(const float*)d_in[5],  (const float*)d_in[13], (const float*)d_in[21]};
  const float* B[3]  = {(const float*)d_in[6],  (const float*)d_in[14], (const float*)d_in[22]};
  const float* Gm[3] = {(const float*)d_in[7],  (const float*)d_in[15], (const float*)d_in[23]};
  const float* BB[3] = {(const float*)d_in[8],  (const float*)d_in[16], (const float*)d_in[24]};
  const float* RM[3] = {(const float*)d_in[9],  (const float*)d_in[17], (const float*)d_in[25]};
  const float* RV[3] = {(const float*)d_in[10], (const float*)d_in[18], (const float*)d_in[26]};
  const float* Wc = (const float*)d_in[27];
  const float* bc = (const float*)d_in[28];

  float* ws = (float*)d_ws;
  float* h      = ws;                                  // NN*FD
  float* xcur   = h + (size_t)NN * FD;                 // NN*FD
  float* als    = xcur + (size_t)NN * FD;              // NN*4
  float* ald    = als + (size_t)NN * 4;                // NN*4
  float* pooled = ald + (size_t)NN * 4;                // NG*FD
  int* cnt      = (int*)(pooled + (size_t)NG * FD);    // NN
  int* row_ptr  = cnt + NN;                            // NN+1
  int* cursor   = row_ptr + NN + 1;                    // NN
  int* col      = cursor + NN;                         // NE

  // ---- CSR by destination (once; shared by all 3 layers) ----
  zero_cnt<<<(NN + 255) / 256, 256, 0, stream>>>(cnt);
  hist_dst<<<(NE + 255) / 256, 256, 0, stream>>>(dst, cnt);
  scan_rowptr<<<1, 256, 0, stream>>>(cnt, row_ptr, cursor);
  scatter_edges<<<(NE + 255) / 256, 256, 0, stream>>>(src, dst, cursor, col);

  const int gemm_blocks = (NN + 31) / 32;
  const int gather_blocks = (NN + 3) / 4;

  for (int layer = 0; layer < 3; ++layer) {
    const float* xin = (layer == 0) ? x : xcur;
    gemm_xw<<<gemm_blocks, 256, 0, stream>>>(xin, W[layer], h);
    if (layer < 2) {
      al_node<4, 32><<<(NN * 4 + 255) / 256, 256, 0, stream>>>(h, AS[layer], AD[layer], als, ald);
      gat_gather<4, 32><<<gather_blocks, 256, 0, stream>>>(row_ptr, col, h, als, ald,
          B[layer], Gm[layer], BB[layer], RM[layer], RV[layer], xcur);
    } else {
      al_node<1, 128><<<(NN + 255) / 256, 256, 0, stream>>>(h, AS[2], AD[2], als, ald);
      gat_gather<1, 128><<<gather_blocks, 256, 0, stream>>>(row_ptr, col, h, als, ald,
          B[2], Gm[2], BB[2], RM[2], RV[2], xcur);
    }
  }
  pool_zero<<<(NG * FD + 255) / 256, 256, 0, stream>>>(pooled);
  pool_sum<<<(NN + 255) / 256, 128, 0, stream>>>(xcur, batch, pooled);
  cls_kernel<<<1, 640, 0, stream>>>(pooled, Wc, bc, (float*)d_out);
}

// Round 3
// 453.599 us; speedup vs baseline: 10.7128x; 1.5116x over previous
//
#include <hip/hip_runtime.h>
#include <math.h>

#define NN 50000
#define NE 800000
#define FD 128
#define NG 64
#define NCLS_ 10
#define EPS_BN 1e-5f
#define SLOPE 0.2f
#define NBLK 196   // ceil(NN/256)

__device__ __forceinline__ float lrelu(float a) { return a > 0.f ? a : SLOPE * a; }

// ---------------- GEMM: h = x @ W, fused attention-logit epilogue ----------------
// Block tile: 32 rows x 128 cols, K-tiled by 32. Thread: 4 rows x 4 cols.
// Epilogue: als[n,hh] / ald[n,hh] via shfl_xor segmented reduction.
template <int H>
__global__ __launch_bounds__(256) void gemm_xw(const float* __restrict__ x,
                                               const float* __restrict__ W,
                                               const float* __restrict__ as_,
                                               const float* __restrict__ ad_,
                                               float* __restrict__ h,
                                               float* __restrict__ als,
                                               float* __restrict__ ald) {
  __shared__ float Wl[32][128];   // 16 KB
  __shared__ float xl[32][32];    // 4 KB
  const int t = threadIdx.x;
  const int cgrp = t & 31;        // 32 col groups
  const int rgrp = t >> 5;        // 8 row groups
  const int c0 = cgrp * 4;
  const int r0 = rgrp * 4;
  const int base = blockIdx.x * 32;

  float acc[4][4];
  #pragma unroll
  for (int i = 0; i < 4; ++i)
    #pragma unroll
    for (int j = 0; j < 4; ++j) acc[i][j] = 0.f;

  for (int kt = 0; kt < 4; ++kt) {
    __syncthreads();
    #pragma unroll
    for (int i = 0; i < 4; ++i) {
      int idx = t + 256 * i;
      int kr = idx >> 5, c4 = (idx & 31) * 4;
      *reinterpret_cast<float4*>(&Wl[kr][c4]) =
          *reinterpret_cast<const float4*>(&W[(kt * 32 + kr) * FD + c4]);
    }
    {
      int r = t >> 3, k4 = (t & 7) * 4;
      int n = base + r;
      float4 v = make_float4(0.f, 0.f, 0.f, 0.f);
      if (n < NN) v = *reinterpret_cast<const float4*>(&x[(size_t)n * FD + kt * 32 + k4]);
      *reinterpret_cast<float4*>(&xl[r][k4]) = v;
    }
    __syncthreads();
    #pragma unroll
    for (int kk = 0; kk < 32; ++kk) {
      float4 wv = *reinterpret_cast<const float4*>(&Wl[kk][c0]);
      #pragma unroll
      for (int i = 0; i < 4; ++i) {
        float xv = xl[r0 + i][kk];
        acc[i][0] = fmaf(xv, wv.x, acc[i][0]);
        acc[i][1] = fmaf(xv, wv.y, acc[i][1]);
        acc[i][2] = fmaf(xv, wv.z, acc[i][2]);
        acc[i][3] = fmaf(xv, wv.w, acc[i][3]);
      }
    }
  }
  // store h
  #pragma unroll
  for (int i = 0; i < 4; ++i) {
    int n = base + r0 + i;
    if (n < NN)
      *reinterpret_cast<float4*>(&h[(size_t)n * FD + c0]) =
          make_float4(acc[i][0], acc[i][1], acc[i][2], acc[i][3]);
  }
  // fused attention logits: als/ald (as_, ad_ flat over H*C=128)
  const float4 asv = *reinterpret_cast<const float4*>(&as_[c0]);
  const float4 adv = *reinterpret_cast<const float4*>(&ad_[c0]);
  float ps[4], pd[4];
  #pragma unroll
  for (int i = 0; i < 4; ++i) {
    ps[i] = acc[i][0] * asv.x + acc[i][1] * asv.y + acc[i][2] * asv.z + acc[i][3] * asv.w;
    pd[i] = acc[i][0] * adv.x + acc[i][1] * adv.y + acc[i][2] * adv.z + acc[i][3] * adv.w;
  }
  constexpr int RW = (H == 4) ? 8 : 32;   // lanes per head segment
  #pragma unroll
  for (int off = 1; off < RW; off <<= 1) {
    #pragma unroll
    for (int i = 0; i < 4; ++i) {
      ps[i] += __shfl_xor(ps[i], off, 64);
      pd[i] += __shfl_xor(pd[i], off, 64);
    }
  }
  if ((cgrp & (RW - 1)) == 0) {
    int hh = (H == 4) ? (cgrp >> 3) : 0;
    #pragma unroll
    for (int i = 0; i < 4; ++i) {
      int n = base + r0 + i;
      if (n < NN) {
        als[n * H + hh] = ps[i];
        ald[n * H + hh] = pd[i];
      }
    }
  }
}

// ---------------- CSR build ----------------
__global__ __launch_bounds__(256) void zero_cnt(int* __restrict__ cnt) {
  int t = blockIdx.x * 256 + threadIdx.x;
  if (t < NN) cnt[t] = 0;
}

__global__ __launch_bounds__(256) void hist_dst(const int* __restrict__ dst,
                                                int* __restrict__ cnt) {
  int e = blockIdx.x * 256 + threadIdx.x;
  if (e < NE) atomicAdd(&cnt[dst[e]], 1);
}

__global__ __launch_bounds__(256) void block_sum(const int* __restrict__ cnt,
                                                 int* __restrict__ bsum) {
  __shared__ int red[256];
  int i = blockIdx.x * 256 + threadIdx.x;
  red[threadIdx.x] = (i < NN) ? cnt[i] : 0;
  __syncthreads();
  for (int s = 128; s > 0; s >>= 1) {
    if (threadIdx.x < s) red[threadIdx.x] += red[threadIdx.x + s];
    __syncthreads();
  }
  if (threadIdx.x == 0) bsum[blockIdx.x] = red[0];
}

__global__ __launch_bounds__(256) void scan_bsum(int* __restrict__ bsum,
                                                 int* __restrict__ row_ptr) {
  __shared__ int sh[256];
  int t = threadIdx.x;
  int v = (t < NBLK) ? bsum[t] : 0;
  sh[t] = v;
  __syncthreads();
  #pragma unroll
  for (int off = 1; off < 256; off <<= 1) {
    int u = (t >= off) ? sh[t - off] : 0;
    __syncthreads();
    sh[t] += u;
    __syncthreads();
  }
  if (t < NBLK) bsum[t] = (t == 0) ? 0 : sh[t - 1];   // exclusive block prefix
  if (t == 0) row_ptr[NN] = sh[NBLK - 1];
}

__global__ __launch_bounds__(256) void write_rowptr(const int* __restrict__ cnt,
                                                    const int* __restrict__ bsum,
                                                    int* __restrict__ row_ptr,
                                                    int* __restrict__ cursor) {
  __shared__ int sh[256];
  int t = threadIdx.x;
  int i = blockIdx.x * 256 + t;
  int v = (i < NN) ? cnt[i] : 0;
  sh[t] = v;
  __syncthreads();
  #pragma unroll
  for (int off = 1; off < 256; off <<= 1) {
    int u = (t >= off) ? sh[t - off] : 0;
    __syncthreads();
    sh[t] += u;
    __syncthreads();
  }
  int excl = sh[t] - v + bsum[blockIdx.x];
  if (i < NN) {
    row_ptr[i] = excl;
    cursor[i] = excl;
  }
}

__global__ __launch_bounds__(256) void scatter_edges(const int* __restrict__ src,
                                                     const int* __restrict__ dst,
                                                     int* __restrict__ cursor,
                                                     int* __restrict__ col) {
  int e = blockIdx.x * 256 + threadIdx.x;
  if (e >= NE) return;
  int pos = atomicAdd(&cursor[dst[e]], 1);
  col[pos] = src[e];
}

// ---------------- fused gather: softmax aggregation + bias + BN + ReLU ----------------
// One 64-lane wave per dst node; lane owns 2 channels. Edge ids preloaded 64-wide.
template <int H, int C>
__global__ __launch_bounds__(256) void gat_gather(const int* __restrict__ row_ptr,
                                                  const int* __restrict__ col,
                                                  const float* __restrict__ h,
                                                  const float* __restrict__ als,
                                                  const float* __restrict__ ald,
                                                  const float* __restrict__ b,
                                                  const float* __restrict__ g,
                                                  const float* __restrict__ bb,
                                                  const float* __restrict__ rm,
                                                  const float* __restrict__ rv,
                                                  float* __restrict__ xnext) {
  int d = (blockIdx.x * 256 + threadIdx.x) >> 6;   // node id
  if (d >= NN) return;
  const int lane = threadIdx.x & 63;
  const int j0 = lane * 2;
  const int hh = j0 / C;

  const float ald_d = ald[d * H + hh];
  float w = __expf(lrelu(als[d * H + hh] + ald_d));   // self-loop
  float2 hv = *reinterpret_cast<const float2*>(h + (size_t)d * FD + j0);
  float accx = w * hv.x, accy = w * hv.y;
  float denom = w;

  const int e0 = row_ptr[d], e1 = row_ptr[d + 1];
  for (int basee = e0; basee < e1; basee += 64) {
    int e = basee + lane;
    int sl = (e < e1) ? col[e] : 0;
    int m = e1 - basee;
    if (m > 64) m = 64;
    for (int k = 0; k < m; ++k) {
      int s = __shfl(sl, k, 64);
      float w2 = __expf(lrelu(als[s * H + hh] + ald_d));
      float2 hs = *reinterpret_cast<const float2*>(h + (size_t)s * FD + j0);
      accx = fmaf(w2, hs.x, accx);
      accy = fmaf(w2, hs.y, accy);
      denom += w2;
    }
  }
  float inv = 1.f / denom;
  int j = j0;
  float v0 = accx * inv + b[j];
  float v1 = accy * inv + b[j + 1];
  v0 = g[j] * (v0 - rm[j]) * rsqrtf(rv[j] + EPS_BN) + bb[j];
  v1 = g[j + 1] * (v1 - rm[j + 1]) * rsqrtf(rv[j + 1] + EPS_BN) + bb[j + 1];
  v0 = v0 > 0.f ? v0 : 0.f;
  v1 = v1 > 0.f ? v1 : 0.f;
  *reinterpret_cast<float2*>(xnext + (size_t)d * FD + j0) = make_float2(v0, v1);
}

// ---------------- pooling ----------------
__global__ __launch_bounds__(256) void pool_zero(float* __restrict__ pooled) {
  int t = blockIdx.x * 256 + threadIdx.x;
  if (t < NG * FD) pooled[t] = 0.f;
}

__global__ __launch_bounds__(128) void pool_sum(const float* __restrict__ x,
                                                const int* __restrict__ batch,
                                                float* __restrict__ pooled) {
  int j = threadIdx.x;                 // 0..127
  int base = blockIdx.x * 128;
  if (base >= NN) return;
  int end = base + 128;
  if (end > NN) end = NN;
  float acc = 0.f;
  int cur = batch[base];
  for (int n = base; n < end; ++n) {
    int gg = batch[n];
    if (gg != cur) {
      atomicAdd(&pooled[cur * FD + j], acc);
      acc = 0.f;
      cur = gg;
    }
    acc += x[(size_t)n * FD + j];
  }
  atomicAdd(&pooled[cur * FD + j], acc);
}

// ---------------- classifier ----------------
__global__ __launch_bounds__(640) void cls_kernel(const float* __restrict__ pooled,
                                                  const float* __restrict__ Wc,
                                                  const float* __restrict__ bc,
                                                  float* __restrict__ out) {
  int t = threadIdx.x;
  if (t >= NG * NCLS_) return;
  int g = t / NCLS_, k = t % NCLS_;
  float acc = bc[k];
  #pragma unroll 16
  for (int j = 0; j < FD; ++j)
    acc = fmaf(pooled[g * FD + j], Wc[j * NCLS_ + k], acc);
  out[t] = acc;
}

extern "C" void kernel_launch(void* const* d_in, const int* in_sizes, int n_in,
                              void* d_out, int out_size, void* d_ws, size_t ws_size,
                              hipStream_t stream) {
  const float* x = (const float*)d_in[0];
  const int* ei = (const int*)d_in[1];
  const int* batch = (const int*)d_in[2];
  const int* src = ei;
  const int* dst = ei + NE;
  const float* W[3]  = {(const float*)d_in[3],  (const float*)d_in[11], (const float*)d_in[19]};
  const float* AS[3] = {(const float*)d_in[4],  (const float*)d_in[12], (const float*)d_in[20]};
  const float* AD[3] = {(const float*)d_in[5],  (const float*)d_in[13], (const float*)d_in[21]};
  const float* B[3]  = {(const float*)d_in[6],  (const float*)d_in[14], (const float*)d_in[22]};
  const float* Gm[3] = {(const float*)d_in[7],  (const float*)d_in[15], (const float*)d_in[23]};
  const float* BB[3] = {(const float*)d_in[8],  (const float*)d_in[16], (const float*)d_in[24]};
  const float* RM[3] = {(const float*)d_in[9],  (const float*)d_in[17], (const float*)d_in[25]};
  const float* RV[3] = {(const float*)d_in[10], (const float*)d_in[18], (const float*)d_in[26]};
  const float* Wc = (const float*)d_in[27];
  const float* bc = (const float*)d_in[28];

  float* ws = (float*)d_ws;
  float* h      = ws;                                  // NN*FD
  float* xcur   = h + (size_t)NN * FD;                 // NN*FD
  float* als    = xcur + (size_t)NN * FD;              // NN*4
  float* ald    = als + (size_t)NN * 4;                // NN*4
  float* pooled = ald + (size_t)NN * 4;                // NG*FD
  int* cnt      = (int*)(pooled + (size_t)NG * FD);    // NN
  int* row_ptr  = cnt + NN;                            // NN+1
  int* cursor   = row_ptr + NN + 1;                    // NN
  int* col      = cursor + NN;                         // NE
  int* bsum     = col + NE;                            // NBLK

  // ---- CSR by destination (shared by all 3 layers) ----
  zero_cnt<<<NBLK, 256, 0, stream>>>(cnt);
  hist_dst<<<(NE + 255) / 256, 256, 0, stream>>>(dst, cnt);
  block_sum<<<NBLK, 256, 0, stream>>>(cnt, bsum);
  scan_bsum<<<1, 256, 0, stream>>>(bsum, row_ptr);
  write_rowptr<<<NBLK, 256, 0, stream>>>(cnt, bsum, row_ptr, cursor);
  scatter_edges<<<(NE + 255) / 256, 256, 0, stream>>>(src, dst, cursor, col);

  const int gemm_blocks = (NN + 31) / 32;
  const int gather_blocks = (NN + 3) / 4;

  for (int layer = 0; layer < 3; ++layer) {
    const float* xin = (layer == 0) ? x : xcur;
    if (layer < 2) {
      gemm_xw<4><<<gemm_blocks, 256, 0, stream>>>(xin, W[layer], AS[layer], AD[layer], h, als, ald);
      gat_gather<4, 32><<<gather_blocks, 256, 0, stream>>>(row_ptr, col, h, als, ald,
          B[layer], Gm[layer], BB[layer], RM[layer], RV[layer], xcur);
    } else {
      gemm_xw<1><<<gemm_blocks, 256, 0, stream>>>(xin, W[2], AS[2], AD[2], h, als, ald);
      gat_gather<1, 128><<<gather_blocks, 256, 0, stream>>>(row_ptr, col, h, als, ald,
          B[2], Gm[2], BB[2], RM[2], RV[2], xcur);
    }
  }
  pool_zero<<<(NG * FD + 255) / 256, 256, 0, stream>>>(pooled);
  pool_sum<<<(NN + 127) / 128, 128, 0, stream>>>(xcur, batch, pooled);
  cls_kernel<<<1, 640, 0, stream>>>(pooled, Wc, bc, (float*)d_out);
}

// Round 4
// 434.552 us; speedup vs baseline: 11.1823x; 1.0438x over previous
//
#include <hip/hip_runtime.h>
#include <math.h>

#define NN 50000
#define NE 800000
#define FD 128
#define NG 64
#define NCLS_ 10
#define EPS_BN 1e-5f
#define SLOPE 0.2f
#define NBLK 196   // ceil(NN/256)

__device__ __forceinline__ float lrelu(float a) { return a > 0.f ? a : SLOPE * a; }

// ---- manual bf16 pack/unpack (RN) ----
__device__ __forceinline__ unsigned int pack_bf2(float a, float b) {
  unsigned int ua = __float_as_uint(a), ub = __float_as_uint(b);
  unsigned int ra = (ua + 0x7fffu + ((ua >> 16) & 1u)) >> 16;
  unsigned int rb = (ub + 0x7fffu + ((ub >> 16) & 1u)) & 0xffff0000u;
  return ra | rb;
}
__device__ __forceinline__ float bf_lo(unsigned int u) { return __uint_as_float(u << 16); }
__device__ __forceinline__ float bf_hi(unsigned int u) { return __uint_as_float(u & 0xffff0000u); }
__device__ __forceinline__ float bf_us(unsigned short s) { return __uint_as_float(((unsigned int)s) << 16); }

// ---------------- GEMM: h = x @ W (bf16 h out), fused attention-logit epilogue ----------------
// Block tile: 32 rows x 128 cols, K-tiled by 32. Thread: 4 rows x 4 cols.
template <int H, bool BFIN>
__global__ __launch_bounds__(256) void gemm_xw(const void* __restrict__ xv,
                                               const float* __restrict__ W,
                                               const float* __restrict__ as_,
                                               const float* __restrict__ ad_,
                                               unsigned int* __restrict__ hq,
                                               float* __restrict__ als,
                                               float* __restrict__ ald) {
  __shared__ float Wl[32][128];   // 16 KB
  __shared__ float xl[32][32];    // 4 KB
  const int t = threadIdx.x;
  const int cgrp = t & 31;        // 32 col groups
  const int rgrp = t >> 5;        // 8 row groups
  const int c0 = cgrp * 4;
  const int r0 = rgrp * 4;
  const int base = blockIdx.x * 32;
  const float* xf = (const float*)xv;
  const unsigned int* xb = (const unsigned int*)xv;   // packed bf16 pairs

  float acc[4][4];
  #pragma unroll
  for (int i = 0; i < 4; ++i)
    #pragma unroll
    for (int j = 0; j < 4; ++j) acc[i][j] = 0.f;

  for (int kt = 0; kt < 4; ++kt) {
    __syncthreads();
    #pragma unroll
    for (int i = 0; i < 4; ++i) {
      int idx = t + 256 * i;
      int kr = idx >> 5, c4 = (idx & 31) * 4;
      *reinterpret_cast<float4*>(&Wl[kr][c4]) =
          *reinterpret_cast<const float4*>(&W[(kt * 32 + kr) * FD + c4]);
    }
    {
      int r = t >> 3, k4 = (t & 7) * 4;
      int n = base + r;
      float4 v = make_float4(0.f, 0.f, 0.f, 0.f);
      if (n < NN) {
        if (BFIN) {
          uint2 u = *reinterpret_cast<const uint2*>(&xb[((size_t)n * FD + kt * 32 + k4) >> 1]);
          v = make_float4(bf_lo(u.x), bf_hi(u.x), bf_lo(u.y), bf_hi(u.y));
        } else {
          v = *reinterpret_cast<const float4*>(&xf[(size_t)n * FD + kt * 32 + k4]);
        }
      }
      *reinterpret_cast<float4*>(&xl[r][k4]) = v;
    }
    __syncthreads();
    #pragma unroll
    for (int kk = 0; kk < 32; ++kk) {
      float4 wv = *reinterpret_cast<const float4*>(&Wl[kk][c0]);
      #pragma unroll
      for (int i = 0; i < 4; ++i) {
        float xv2 = xl[r0 + i][kk];
        acc[i][0] = fmaf(xv2, wv.x, acc[i][0]);
        acc[i][1] = fmaf(xv2, wv.y, acc[i][1]);
        acc[i][2] = fmaf(xv2, wv.z, acc[i][2]);
        acc[i][3] = fmaf(xv2, wv.w, acc[i][3]);
      }
    }
  }
  // store h (packed bf16)
  #pragma unroll
  for (int i = 0; i < 4; ++i) {
    int n = base + r0 + i;
    if (n < NN) {
      uint2 p;
      p.x = pack_bf2(acc[i][0], acc[i][1]);
      p.y = pack_bf2(acc[i][2], acc[i][3]);
      *reinterpret_cast<uint2*>(&hq[(size_t)n * (FD / 2) + (c0 >> 1)]) = p;
    }
  }
  // fused attention logits (fp32 accs)
  const float4 asv = *reinterpret_cast<const float4*>(&as_[c0]);
  const float4 adv = *reinterpret_cast<const float4*>(&ad_[c0]);
  float ps[4], pd[4];
  #pragma unroll
  for (int i = 0; i < 4; ++i) {
    ps[i] = acc[i][0] * asv.x + acc[i][1] * asv.y + acc[i][2] * asv.z + acc[i][3] * asv.w;
    pd[i] = acc[i][0] * adv.x + acc[i][1] * adv.y + acc[i][2] * adv.z + acc[i][3] * adv.w;
  }
  constexpr int RW = (H == 4) ? 8 : 32;   // lanes per head segment
  #pragma unroll
  for (int off = 1; off < RW; off <<= 1) {
    #pragma unroll
    for (int i = 0; i < 4; ++i) {
      ps[i] += __shfl_xor(ps[i], off, 64);
      pd[i] += __shfl_xor(pd[i], off, 64);
    }
  }
  if ((cgrp & (RW - 1)) == 0) {
    int hh = (H == 4) ? (cgrp >> 3) : 0;
    #pragma unroll
    for (int i = 0; i < 4; ++i) {
      int n = base + r0 + i;
      if (n < NN) {
        als[n * H + hh] = ps[i];
        ald[n * H + hh] = pd[i];
      }
    }
  }
}

// ---------------- CSR build ----------------
__global__ __launch_bounds__(256) void zero_cnt(int* __restrict__ cnt) {
  int t = blockIdx.x * 256 + threadIdx.x;
  if (t < NN) cnt[t] = 0;
}

__global__ __launch_bounds__(256) void hist_dst(const int* __restrict__ dst,
                                                int* __restrict__ cnt) {
  int e = blockIdx.x * 256 + threadIdx.x;
  if (e < NE) atomicAdd(&cnt[dst[e]], 1);
}

__global__ __launch_bounds__(256) void block_sum(const int* __restrict__ cnt,
                                                 int* __restrict__ bsum) {
  __shared__ int red[256];
  int i = blockIdx.x * 256 + threadIdx.x;
  red[threadIdx.x] = (i < NN) ? cnt[i] : 0;
  __syncthreads();
  for (int s = 128; s > 0; s >>= 1) {
    if (threadIdx.x < s) red[threadIdx.x] += red[threadIdx.x + s];
    __syncthreads();
  }
  if (threadIdx.x == 0) bsum[blockIdx.x] = red[0];
}

__global__ __launch_bounds__(256) void scan_bsum(int* __restrict__ bsum,
                                                 int* __restrict__ row_ptr) {
  __shared__ int sh[256];
  int t = threadIdx.x;
  int v = (t < NBLK) ? bsum[t] : 0;
  sh[t] = v;
  __syncthreads();
  #pragma unroll
  for (int off = 1; off < 256; off <<= 1) {
    int u = (t >= off) ? sh[t - off] : 0;
    __syncthreads();
    sh[t] += u;
    __syncthreads();
  }
  if (t < NBLK) bsum[t] = (t == 0) ? 0 : sh[t - 1];   // exclusive block prefix
  if (t == 0) row_ptr[NN] = sh[NBLK - 1];
}

__global__ __launch_bounds__(256) void write_rowptr(const int* __restrict__ cnt,
                                                    const int* __restrict__ bsum,
                                                    int* __restrict__ row_ptr,
                                                    int* __restrict__ cursor) {
  __shared__ int sh[256];
  int t = threadIdx.x;
  int i = blockIdx.x * 256 + t;
  int v = (i < NN) ? cnt[i] : 0;
  sh[t] = v;
  __syncthreads();
  #pragma unroll
  for (int off = 1; off < 256; off <<= 1) {
    int u = (t >= off) ? sh[t - off] : 0;
    __syncthreads();
    sh[t] += u;
    __syncthreads();
  }
  int excl = sh[t] - v + bsum[blockIdx.x];
  if (i < NN) {
    row_ptr[i] = excl;
    cursor[i] = excl;
  }
}

__global__ __launch_bounds__(256) void scatter_edges(const int* __restrict__ src,
                                                     const int* __restrict__ dst,
                                                     int* __restrict__ cursor,
                                                     int* __restrict__ col) {
  int e = blockIdx.x * 256 + threadIdx.x;
  if (e >= NE) return;
  int pos = atomicAdd(&cursor[dst[e]], 1);
  col[pos] = src[e];
}

// ---------------- fused gather: softmax aggregation + bias + BN + ReLU ----------------
// One 64-lane wave per dst node; lane owns 2 channels (one packed bf16 pair).
template <int H, int C>
__global__ __launch_bounds__(256) void gat_gather(const int* __restrict__ row_ptr,
                                                  const int* __restrict__ col,
                                                  const unsigned int* __restrict__ hq,
                                                  const float* __restrict__ als,
                                                  const float* __restrict__ ald,
                                                  const float* __restrict__ b,
                                                  const float* __restrict__ g,
                                                  const float* __restrict__ bb,
                                                  const float* __restrict__ rm,
                                                  const float* __restrict__ rv,
                                                  unsigned int* __restrict__ xq) {
  int d = (blockIdx.x * 256 + threadIdx.x) >> 6;   // node id
  if (d >= NN) return;
  const int lane = threadIdx.x & 63;
  const int j0 = lane * 2;
  const int hh = j0 / C;

  const float ald_d = ald[d * H + hh];
  float w = __expf(lrelu(als[d * H + hh] + ald_d));   // self-loop
  unsigned int hu = hq[(size_t)d * (FD / 2) + lane];
  float accx = w * bf_lo(hu), accy = w * bf_hi(hu);
  float denom = w;

  const int e0 = row_ptr[d], e1 = row_ptr[d + 1];
  for (int basee = e0; basee < e1; basee += 64) {
    int e = basee + lane;
    int sl = (e < e1) ? col[e] : 0;
    int m = e1 - basee;
    if (m > 64) m = 64;
    for (int k = 0; k < m; ++k) {
      int s = __shfl(sl, k, 64);
      float w2 = __expf(lrelu(als[s * H + hh] + ald_d));
      unsigned int hs = hq[(size_t)s * (FD / 2) + lane];
      accx = fmaf(w2, bf_lo(hs), accx);
      accy = fmaf(w2, bf_hi(hs), accy);
      denom += w2;
    }
  }
  float inv = 1.f / denom;
  int j = j0;
  float v0 = accx * inv + b[j];
  float v1 = accy * inv + b[j + 1];
  v0 = g[j] * (v0 - rm[j]) * rsqrtf(rv[j] + EPS_BN) + bb[j];
  v1 = g[j + 1] * (v1 - rm[j + 1]) * rsqrtf(rv[j + 1] + EPS_BN) + bb[j + 1];
  v0 = v0 > 0.f ? v0 : 0.f;
  v1 = v1 > 0.f ? v1 : 0.f;
  xq[(size_t)d * (FD / 2) + lane] = pack_bf2(v0, v1);
}

// ---------------- pooling ----------------
__global__ __launch_bounds__(256) void pool_zero(float* __restrict__ pooled) {
  int t = blockIdx.x * 256 + threadIdx.x;
  if (t < NG * FD) pooled[t] = 0.f;
}

__global__ __launch_bounds__(128) void pool_sum(const unsigned short* __restrict__ xb,
                                                const int* __restrict__ batch,
                                                float* __restrict__ pooled) {
  int j = threadIdx.x;                 // 0..127
  int base = blockIdx.x * 128;
  if (base >= NN) return;
  int end = base + 128;
  if (end > NN) end = NN;
  float acc = 0.f;
  int cur = batch[base];
  for (int n = base; n < end; ++n) {
    int gg = batch[n];
    if (gg != cur) {
      atomicAdd(&pooled[cur * FD + j], acc);
      acc = 0.f;
      cur = gg;
    }
    acc += bf_us(xb[(size_t)n * FD + j]);
  }
  atomicAdd(&pooled[cur * FD + j], acc);
}

// ---------------- classifier ----------------
__global__ __launch_bounds__(640) void cls_kernel(const float* __restrict__ pooled,
                                                  const float* __restrict__ Wc,
                                                  const float* __restrict__ bc,
                                                  float* __restrict__ out) {
  int t = threadIdx.x;
  if (t >= NG * NCLS_) return;
  int g = t / NCLS_, k = t % NCLS_;
  float acc = bc[k];
  #pragma unroll 16
  for (int j = 0; j < FD; ++j)
    acc = fmaf(pooled[g * FD + j], Wc[j * NCLS_ + k], acc);
  out[t] = acc;
}

extern "C" void kernel_launch(void* const* d_in, const int* in_sizes, int n_in,
                              void* d_out, int out_size, void* d_ws, size_t ws_size,
                              hipStream_t stream) {
  const float* x = (const float*)d_in[0];
  const int* ei = (const int*)d_in[1];
  const int* batch = (const int*)d_in[2];
  const int* src = ei;
  const int* dst = ei + NE;
  const float* W[3]  = {(const float*)d_in[3],  (const float*)d_in[11], (const float*)d_in[19]};
  const float* AS[3] = {(const float*)d_in[4],  (const float*)d_in[12], (const float*)d_in[20]};
  const float* AD[3] = {(const float*)d_in[5],  (const float*)d_in[13], (const float*)d_in[21]};
  const float* B[3]  = {(const float*)d_in[6],  (const float*)d_in[14], (const float*)d_in[22]};
  const float* Gm[3] = {(const float*)d_in[7],  (const float*)d_in[15], (const float*)d_in[23]};
  const float* BB[3] = {(const float*)d_in[8],  (const float*)d_in[16], (const float*)d_in[24]};
  const float* RM[3] = {(const float*)d_in[9],  (const float*)d_in[17], (const float*)d_in[25]};
  const float* RV[3] = {(const float*)d_in[10], (const float*)d_in[18], (const float*)d_in[26]};
  const float* Wc = (const float*)d_in[27];
  const float* bc = (const float*)d_in[28];

  unsigned int* hq = (unsigned int*)d_ws;              // NN*64 packed bf16 pairs
  unsigned int* xq = hq + (size_t)NN * (FD / 2);       // NN*64
  float* als    = (float*)(xq + (size_t)NN * (FD / 2)); // NN*4
  float* ald    = als + (size_t)NN * 4;                // NN*4
  float* pooled = ald + (size_t)NN * 4;                // NG*FD
  int* cnt      = (int*)(pooled + (size_t)NG * FD);    // NN
  int* row_ptr  = cnt + NN;                            // NN+1
  int* cursor   = row_ptr + NN + 1;                    // NN
  int* col      = cursor + NN;                         // NE
  int* bsum     = col + NE;                            // NBLK

  // ---- CSR by destination (shared by all 3 layers) ----
  zero_cnt<<<NBLK, 256, 0, stream>>>(cnt);
  hist_dst<<<(NE + 255) / 256, 256, 0, stream>>>(dst, cnt);
  block_sum<<<NBLK, 256, 0, stream>>>(cnt, bsum);
  scan_bsum<<<1, 256, 0, stream>>>(bsum, row_ptr);
  write_rowptr<<<NBLK, 256, 0, stream>>>(cnt, bsum, row_ptr, cursor);
  scatter_edges<<<(NE + 255) / 256, 256, 0, stream>>>(src, dst, cursor, col);

  const int gemm_blocks = (NN + 31) / 32;
  const int gather_blocks = (NN + 3) / 4;

  // layer 0 (fp32 input)
  gemm_xw<4, false><<<gemm_blocks, 256, 0, stream>>>(x, W[0], AS[0], AD[0], hq, als, ald);
  gat_gather<4, 32><<<gather_blocks, 256, 0, stream>>>(row_ptr, col, hq, als, ald,
      B[0], Gm[0], BB[0], RM[0], RV[0], xq);
  // layer 1 (bf16 input)
  gemm_xw<4, true><<<gemm_blocks, 256, 0, stream>>>(xq, W[1], AS[1], AD[1], hq, als, ald);
  gat_gather<4, 32><<<gather_blocks, 256, 0, stream>>>(row_ptr, col, hq, als, ald,
      B[1], Gm[1], BB[1], RM[1], RV[1], xq);
  // layer 2 (bf16 input, single head)
  gemm_xw<1, true><<<gemm_blocks, 256, 0, stream>>>(xq, W[2], AS[2], AD[2], hq, als, ald);
  gat_gather<1, 128><<<gather_blocks, 256, 0, stream>>>(row_ptr, col, hq, als, ald,
      B[2], Gm[2], BB[2], RM[2], RV[2], xq);

  pool_zero<<<(NG * FD + 255) / 256, 256, 0, stream>>>(pooled);
  pool_sum<<<(NN + 127) / 128, 128, 0, stream>>>((const unsigned short*)xq, batch, pooled);
  cls_kernel<<<1, 640, 0, stream>>>(pooled, Wc, bc, (float*)d_out);
}

// Round 5
// 427.285 us; speedup vs baseline: 11.3725x; 1.0170x over previous
//
#include <hip/hip_runtime.h>
#include <math.h>

#define NN 50000
#define NN_PAD 50048   // 782*64, padded rows for MFMA tiles
#define NE 800000
#define FD 128
#define NG 64
#define NCLS_ 10
#define EPS_BN 1e-5f
#define SLOPE 0.2f
#define NBLK 196   // ceil(NN/256)

typedef __attribute__((ext_vector_type(8))) short bf16x8;
typedef __attribute__((ext_vector_type(4))) float f32x4;
typedef unsigned short ushort_t;
typedef unsigned int uint_t;

__device__ __forceinline__ float lrelu(float a) { return a > 0.f ? a : SLOPE * a; }

// ---- manual bf16 pack/unpack (RN) ----
__device__ __forceinline__ unsigned int pack_bf2(float a, float b) {
  unsigned int ua = __float_as_uint(a), ub = __float_as_uint(b);
  unsigned int ra = (ua + 0x7fffu + ((ua >> 16) & 1u)) >> 16;
  unsigned int rb = (ub + 0x7fffu + ((ub >> 16) & 1u)) & 0xffff0000u;
  return ra | rb;
}
__device__ __forceinline__ float bf_lo(unsigned int u) { return __uint_as_float(u << 16); }
__device__ __forceinline__ float bf_hi(unsigned int u) { return __uint_as_float(u & 0xffff0000u); }
__device__ __forceinline__ float bf_us(unsigned short s) { return __uint_as_float(((unsigned int)s) << 16); }

// ---------------- W transpose + bf16 pack: Wt[n][k] = bf16(W[k][n]) ----------------
__global__ __launch_bounds__(256) void wt_pack(const float* __restrict__ W,
                                               ushort_t* __restrict__ Wt) {
  int t = blockIdx.x * 256 + threadIdx.x;
  if (t >= FD * FD) return;
  int n = t & 127, k = t >> 7;
  unsigned int u = __float_as_uint(W[k * FD + n]);
  Wt[(size_t)n * FD + k] = (ushort_t)((u + 0x7fffu + ((u >> 16) & 1u)) >> 16);
}

// ---------------- MFMA GEMM: h = x @ W (bf16), fused attention-logit epilogue ----------------
// 4 waves/block; wave computes 16 rows x 128 cols via 8 col-tiles of 16x16x32.
template <int H, bool BFIN>
__global__ __launch_bounds__(256) void gemm_mfma(const void* __restrict__ xin,
                                                 const ushort_t* __restrict__ Wt,
                                                 const float* __restrict__ as_,
                                                 const float* __restrict__ ad_,
                                                 uint_t* __restrict__ hq,
                                                 float* __restrict__ als,
                                                 float* __restrict__ ald) {
  const int l = threadIdx.x & 63;
  const int wv = threadIdx.x >> 6;
  const int n0 = blockIdx.x * 64 + wv * 16;
  const int r = l & 15;          // A-row / B-col within tile
  const int kb = l >> 4;         // k-block (8 elems each)
  const int nr = min(n0 + r, NN - 1);   // clamped A row (results for pad rows discarded)

  f32x4 acc[8];
  #pragma unroll
  for (int ct = 0; ct < 8; ++ct)
    #pragma unroll
    for (int j = 0; j < 4; ++j) acc[ct][j] = 0.f;

  #pragma unroll
  for (int kt = 0; kt < 4; ++kt) {
    bf16x8 af;
    if (BFIN) {
      af = *reinterpret_cast<const bf16x8*>(
          (const ushort_t*)xin + (size_t)nr * FD + kt * 32 + kb * 8);
    } else {
      const float* xf = (const float*)xin + (size_t)nr * FD + kt * 32 + kb * 8;
      float4 f0 = *reinterpret_cast<const float4*>(xf);
      float4 f1 = *reinterpret_cast<const float4*>(xf + 4);
      union { bf16x8 v; unsigned int u[4]; } cvt;
      cvt.u[0] = pack_bf2(f0.x, f0.y);
      cvt.u[1] = pack_bf2(f0.z, f0.w);
      cvt.u[2] = pack_bf2(f1.x, f1.y);
      cvt.u[3] = pack_bf2(f1.z, f1.w);
      af = cvt.v;
    }
    #pragma unroll
    for (int ct = 0; ct < 8; ++ct) {
      bf16x8 bf = *reinterpret_cast<const bf16x8*>(
          &Wt[(size_t)(ct * 16 + r) * FD + kt * 32 + kb * 8]);
      acc[ct] = __builtin_amdgcn_mfma_f32_16x16x32_bf16(af, bf, acc[ct], 0, 0, 0);
    }
  }

  // ---- h store (packed bf16 pairs) ----
  // C layout: row=(l>>4)*4+j, col=ct*16+(l&15)
  #pragma unroll
  for (int ct = 0; ct < 8; ++ct)
    #pragma unroll
    for (int j = 0; j < 4; ++j) {
      float v = acc[ct][j];
      float p = __shfl_xor(v, 1, 64);
      if (!(l & 1)) {
        int n = n0 + (l >> 4) * 4 + j;
        if (n < NN) hq[(size_t)n * (FD / 2) + ct * 8 + (r >> 1)] = pack_bf2(v, p);
      }
    }

  // ---- fused attention logits ----
  if (H == 4) {
    float ps[4][4], pd[4][4];
    #pragma unroll
    for (int j = 0; j < 4; ++j)
      #pragma unroll
      for (int hd = 0; hd < 4; ++hd) { ps[j][hd] = 0.f; pd[j][hd] = 0.f; }
    #pragma unroll
    for (int ct = 0; ct < 8; ++ct) {
      float a_s = as_[ct * 16 + r];
      float a_d = ad_[ct * 16 + r];
      int hd = ct >> 1;
      #pragma unroll
      for (int j = 0; j < 4; ++j) {
        ps[j][hd] = fmaf(acc[ct][j], a_s, ps[j][hd]);
        pd[j][hd] = fmaf(acc[ct][j], a_d, pd[j][hd]);
      }
    }
    #pragma unroll
    for (int off = 1; off < 16; off <<= 1)
      #pragma unroll
      for (int j = 0; j < 4; ++j)
        #pragma unroll
        for (int hd = 0; hd < 4; ++hd) {
          ps[j][hd] += __shfl_xor(ps[j][hd], off, 64);
          pd[j][hd] += __shfl_xor(pd[j][hd], off, 64);
        }
    if (r == 0) {
      #pragma unroll
      for (int j = 0; j < 4; ++j) {
        int n = n0 + (l >> 4) * 4 + j;
        if (n < NN) {
          *reinterpret_cast<float4*>(&als[n * 4]) =
              make_float4(ps[j][0], ps[j][1], ps[j][2], ps[j][3]);
          *reinterpret_cast<float4*>(&ald[n * 4]) =
              make_float4(pd[j][0], pd[j][1], pd[j][2], pd[j][3]);
        }
      }
    }
  } else {
    float ps[4], pd[4];
    #pragma unroll
    for (int j = 0; j < 4; ++j) { ps[j] = 0.f; pd[j] = 0.f; }
    #pragma unroll
    for (int ct = 0; ct < 8; ++ct) {
      float a_s = as_[ct * 16 + r];
      float a_d = ad_[ct * 16 + r];
      #pragma unroll
      for (int j = 0; j < 4; ++j) {
        ps[j] = fmaf(acc[ct][j], a_s, ps[j]);
        pd[j] = fmaf(acc[ct][j], a_d, pd[j]);
      }
    }
    #pragma unroll
    for (int off = 1; off < 16; off <<= 1)
      #pragma unroll
      for (int j = 0; j < 4; ++j) {
        ps[j] += __shfl_xor(ps[j], off, 64);
        pd[j] += __shfl_xor(pd[j], off, 64);
      }
    if (r == 0) {
      #pragma unroll
      for (int j = 0; j < 4; ++j) {
        int n = n0 + (l >> 4) * 4 + j;
        if (n < NN) { als[n] = ps[j]; ald[n] = pd[j]; }
      }
    }
  }
}

// ---------------- CSR build ----------------
__global__ __launch_bounds__(256) void zero_cnt(int* __restrict__ cnt) {
  int t = blockIdx.x * 256 + threadIdx.x;
  if (t < NN) cnt[t] = 0;
}

__global__ __launch_bounds__(256) void hist_dst(const int* __restrict__ dst,
                                                int* __restrict__ cnt) {
  int e = blockIdx.x * 256 + threadIdx.x;
  if (e < NE) atomicAdd(&cnt[dst[e]], 1);
}

__global__ __launch_bounds__(256) void block_sum(const int* __restrict__ cnt,
                                                 int* __restrict__ bsum) {
  __shared__ int red[256];
  int i = blockIdx.x * 256 + threadIdx.x;
  red[threadIdx.x] = (i < NN) ? cnt[i] : 0;
  __syncthreads();
  for (int s = 128; s > 0; s >>= 1) {
    if (threadIdx.x < s) red[threadIdx.x] += red[threadIdx.x + s];
    __syncthreads();
  }
  if (threadIdx.x == 0) bsum[blockIdx.x] = red[0];
}

__global__ __launch_bounds__(256) void scan_bsum(int* __restrict__ bsum,
                                                 int* __restrict__ row_ptr) {
  __shared__ int sh[256];
  int t = threadIdx.x;
  int v = (t < NBLK) ? bsum[t] : 0;
  sh[t] = v;
  __syncthreads();
  #pragma unroll
  for (int off = 1; off < 256; off <<= 1) {
    int u = (t >= off) ? sh[t - off] : 0;
    __syncthreads();
    sh[t] += u;
    __syncthreads();
  }
  if (t < NBLK) bsum[t] = (t == 0) ? 0 : sh[t - 1];
  if (t == 0) row_ptr[NN] = sh[NBLK - 1];
}

__global__ __launch_bounds__(256) void write_rowptr(const int* __restrict__ cnt,
                                                    const int* __restrict__ bsum,
                                                    int* __restrict__ row_ptr,
                                                    int* __restrict__ cursor) {
  __shared__ int sh[256];
  int t = threadIdx.x;
  int i = blockIdx.x * 256 + t;
  int v = (i < NN) ? cnt[i] : 0;
  sh[t] = v;
  __syncthreads();
  #pragma unroll
  for (int off = 1; off < 256; off <<= 1) {
    int u = (t >= off) ? sh[t - off] : 0;
    __syncthreads();
    sh[t] += u;
    __syncthreads();
  }
  int excl = sh[t] - v + bsum[blockIdx.x];
  if (i < NN) {
    row_ptr[i] = excl;
    cursor[i] = excl;
  }
}

__global__ __launch_bounds__(256) void scatter_edges(const int* __restrict__ src,
                                                     const int* __restrict__ dst,
                                                     int* __restrict__ cursor,
                                                     int* __restrict__ col) {
  int e = blockIdx.x * 256 + threadIdx.x;
  if (e >= NE) return;
  int pos = atomicAdd(&cursor[dst[e]], 1);
  col[pos] = src[e];
}

// ---------------- fused gather: 2-phase softmax aggregation + bias + BN + ReLU ----------------
// One 64-lane wave per dst node; lane owns 2 channels (one packed bf16 pair).
// Phase 1 (per chunk): lane (eidx, head) computes one edge weight. Phase 2: shfl-broadcast.
template <int H, int C>
__global__ __launch_bounds__(256) void gat_gather(const int* __restrict__ row_ptr,
                                                  const int* __restrict__ col,
                                                  const uint_t* __restrict__ hq,
                                                  const float* __restrict__ als,
                                                  const float* __restrict__ ald,
                                                  const float* __restrict__ b,
                                                  const float* __restrict__ g,
                                                  const float* __restrict__ bb,
                                                  const float* __restrict__ rm,
                                                  const float* __restrict__ rv,
                                                  uint_t* __restrict__ xq) {
  int d = (blockIdx.x * 256 + threadIdx.x) >> 6;
  if (d >= NN) return;
  const int lane = threadIdx.x & 63;
  const int j0 = lane * 2;
  const int oh = j0 / C;                 // own head (H=4: lane>>4; H=1: 0)

  const float aldo = ald[d * H + oh];
  const float wself = __expf(lrelu(als[d * H + oh] + aldo));
  uint_t hu = hq[(size_t)d * (FD / 2) + lane];
  float accx = wself * bf_lo(hu), accy = wself * bf_hi(hu);
  float dpart = 0.f;

  const int e0 = row_ptr[d], e1 = row_ptr[d + 1];
  constexpr int CH = (H == 4) ? 16 : 64;
  for (int base = e0; base < e1; base += CH) {
    int m = e1 - base;
    if (m > CH) m = CH;
    const int eidx = (H == 4) ? (lane & 15) : lane;
    int sl = 0;
    float w = 0.f;
    if (eidx < m) {
      sl = col[base + eidx];
      w = __expf(lrelu(als[sl * H + oh] + aldo));
    }
    dpart += w;
    for (int k = 0; k < m; ++k) {
      float wk = (H == 4) ? __shfl(w, (lane & 48) + k, 64) : __shfl(w, k, 64);
      int sk = __shfl(sl, k, 64);
      uint_t hs = hq[(size_t)sk * (FD / 2) + lane];
      accx = fmaf(wk, bf_lo(hs), accx);
      accy = fmaf(wk, bf_hi(hs), accy);
    }
  }
  // reduce edge-denominator partials within head group
  #pragma unroll
  for (int off = 1; off < ((H == 4) ? 16 : 64); off <<= 1)
    dpart += __shfl_xor(dpart, off, 64);
  float denom = dpart + wself;

  float inv = 1.f / denom;
  int j = j0;
  float v0 = accx * inv + b[j];
  float v1 = accy * inv + b[j + 1];
  v0 = g[j] * (v0 - rm[j]) * rsqrtf(rv[j] + EPS_BN) + bb[j];
  v1 = g[j + 1] * (v1 - rm[j + 1]) * rsqrtf(rv[j + 1] + EPS_BN) + bb[j + 1];
  v0 = v0 > 0.f ? v0 : 0.f;
  v1 = v1 > 0.f ? v1 : 0.f;
  xq[(size_t)d * (FD / 2) + lane] = pack_bf2(v0, v1);
}

// ---------------- pooling ----------------
__global__ __launch_bounds__(256) void pool_zero(float* __restrict__ pooled) {
  int t = blockIdx.x * 256 + threadIdx.x;
  if (t < NG * FD) pooled[t] = 0.f;
}

__global__ __launch_bounds__(128) void pool_sum(const ushort_t* __restrict__ xb,
                                                const int* __restrict__ batch,
                                                float* __restrict__ pooled) {
  int j = threadIdx.x;
  int base = blockIdx.x * 128;
  if (base >= NN) return;
  int end = base + 128;
  if (end > NN) end = NN;
  float acc = 0.f;
  int cur = batch[base];
  for (int n = base; n < end; ++n) {
    int gg = batch[n];
    if (gg != cur) {
      atomicAdd(&pooled[cur * FD + j], acc);
      acc = 0.f;
      cur = gg;
    }
    acc += bf_us(xb[(size_t)n * FD + j]);
  }
  atomicAdd(&pooled[cur * FD + j], acc);
}

// ---------------- classifier ----------------
__global__ __launch_bounds__(640) void cls_kernel(const float* __restrict__ pooled,
                                                  const float* __restrict__ Wc,
                                                  const float* __restrict__ bc,
                                                  float* __restrict__ out) {
  int t = threadIdx.x;
  if (t >= NG * NCLS_) return;
  int g = t / NCLS_, k = t % NCLS_;
  float acc = bc[k];
  #pragma unroll 16
  for (int j = 0; j < FD; ++j)
    acc = fmaf(pooled[g * FD + j], Wc[j * NCLS_ + k], acc);
  out[t] = acc;
}

extern "C" void kernel_launch(void* const* d_in, const int* in_sizes, int n_in,
                              void* d_out, int out_size, void* d_ws, size_t ws_size,
                              hipStream_t stream) {
  const float* x = (const float*)d_in[0];
  const int* ei = (const int*)d_in[1];
  const int* batch = (const int*)d_in[2];
  const int* src = ei;
  const int* dst = ei + NE;
  const float* W[3]  = {(const float*)d_in[3],  (const float*)d_in[11], (const float*)d_in[19]};
  const float* AS[3] = {(const float*)d_in[4],  (const float*)d_in[12], (const float*)d_in[20]};
  const float* AD[3] = {(const float*)d_in[5],  (const float*)d_in[13], (const float*)d_in[21]};
  const float* B[3]  = {(const float*)d_in[6],  (const float*)d_in[14], (const float*)d_in[22]};
  const float* Gm[3] = {(const float*)d_in[7],  (const float*)d_in[15], (const float*)d_in[23]};
  const float* BB[3] = {(const float*)d_in[8],  (const float*)d_in[16], (const float*)d_in[24]};
  const float* RM[3] = {(const float*)d_in[9],  (const float*)d_in[17], (const float*)d_in[25]};
  const float* RV[3] = {(const float*)d_in[10], (const float*)d_in[18], (const float*)d_in[26]};
  const float* Wc = (const float*)d_in[27];
  const float* bc = (const float*)d_in[28];

  uint_t* hq    = (uint_t*)d_ws;                          // NN_PAD*64
  uint_t* xq    = hq + (size_t)NN_PAD * (FD / 2);         // NN_PAD*64
  float* als    = (float*)(xq + (size_t)NN_PAD * (FD / 2)); // NN*4
  float* ald    = als + (size_t)NN * 4;                   // NN*4
  float* pooled = ald + (size_t)NN * 4;                   // NG*FD
  ushort_t* Wt  = (ushort_t*)(pooled + (size_t)NG * FD);  // 128*128 bf16
  int* cnt      = (int*)(Wt + (size_t)FD * FD);           // NN
  int* row_ptr  = cnt + NN;                               // NN+1
  int* cursor   = row_ptr + NN + 1;                       // NN
  int* col      = cursor + NN;                            // NE
  int* bsum     = col + NE;                               // NBLK

  // ---- CSR by destination (shared by all 3 layers) ----
  zero_cnt<<<NBLK, 256, 0, stream>>>(cnt);
  hist_dst<<<(NE + 255) / 256, 256, 0, stream>>>(dst, cnt);
  block_sum<<<NBLK, 256, 0, stream>>>(cnt, bsum);
  scan_bsum<<<1, 256, 0, stream>>>(bsum, row_ptr);
  write_rowptr<<<NBLK, 256, 0, stream>>>(cnt, bsum, row_ptr, cursor);
  scatter_edges<<<(NE + 255) / 256, 256, 0, stream>>>(src, dst, cursor, col);

  const int gemm_blocks = NN_PAD / 64;     // 782
  const int gather_blocks = (NN + 3) / 4;
  const int wt_blocks = (FD * FD + 255) / 256;

  // layer 0 (fp32 input)
  wt_pack<<<wt_blocks, 256, 0, stream>>>(W[0], Wt);
  gemm_mfma<4, false><<<gemm_blocks, 256, 0, stream>>>(x, Wt, AS[0], AD[0], hq, als, ald);
  gat_gather<4, 32><<<gather_blocks, 256, 0, stream>>>(row_ptr, col, hq, als, ald,
      B[0], Gm[0], BB[0], RM[0], RV[0], xq);
  // layer 1 (bf16 input)
  wt_pack<<<wt_blocks, 256, 0, stream>>>(W[1], Wt);
  gemm_mfma<4, true><<<gemm_blocks, 256, 0, stream>>>(xq, Wt, AS[1], AD[1], hq, als, ald);
  gat_gather<4, 32><<<gather_blocks, 256, 0, stream>>>(row_ptr, col, hq, als, ald,
      B[1], Gm[1], BB[1], RM[1], RV[1], xq);
  // layer 2 (bf16 input, single head)
  wt_pack<<<wt_blocks, 256, 0, stream>>>(W[2], Wt);
  gemm_mfma<1, true><<<gemm_blocks, 256, 0, stream>>>(xq, Wt, AS[2], AD[2], hq, als, ald);
  gat_gather<1, 128><<<gather_blocks, 256, 0, stream>>>(row_ptr, col, hq, als, ald,
      B[2], Gm[2], BB[2], RM[2], RV[2], xq);

  pool_zero<<<(NG * FD + 255) / 256, 256, 0, stream>>>(pooled);
  pool_sum<<<(NN + 127) / 128, 128, 0, stream>>>((const ushort_t*)xq, batch, pooled);
  cls_kernel<<<1, 640, 0, stream>>>(pooled, Wc, bc, (float*)d_out);
}

// Round 6
// 378.337 us; speedup vs baseline: 12.8438x; 1.1294x over previous
//
#include <hip/hip_runtime.h>
#include <math.h>

#define NN 50000
#define NN_PAD 50048   // 782*64, padded rows for MFMA tiles
#define NE 800000
#define FD 128
#define NG 64
#define NCLS_ 10
#define EPS_BN 1e-5f
#define SLOPE 0.2f
#define NBLK 196   // ceil(NN/256)

typedef __attribute__((ext_vector_type(8))) short bf16x8;
typedef __attribute__((ext_vector_type(4))) float f32x4;
typedef unsigned short ushort_t;
typedef unsigned int uint_t;

__device__ __forceinline__ float lrelu(float a) { return a > 0.f ? a : SLOPE * a; }

// ---- manual bf16 pack/unpack (RN) ----
__device__ __forceinline__ unsigned int pack_bf2(float a, float b) {
  unsigned int ua = __float_as_uint(a), ub = __float_as_uint(b);
  unsigned int ra = (ua + 0x7fffu + ((ua >> 16) & 1u)) >> 16;
  unsigned int rb = (ub + 0x7fffu + ((ub >> 16) & 1u)) & 0xffff0000u;
  return ra | rb;
}
__device__ __forceinline__ float bf_lo(unsigned int u) { return __uint_as_float(u << 16); }
__device__ __forceinline__ float bf_hi(unsigned int u) { return __uint_as_float(u & 0xffff0000u); }
__device__ __forceinline__ float bf_us(unsigned short s) { return __uint_as_float(((unsigned int)s) << 16); }

// ---------------- W transpose + bf16 pack, all 3 layers in one launch ----------------
__global__ __launch_bounds__(256) void wt_pack3(const float* __restrict__ W0,
                                                const float* __restrict__ W1,
                                                const float* __restrict__ W2,
                                                ushort_t* __restrict__ Wt) {
  int t = blockIdx.x * 256 + threadIdx.x;
  if (t >= 3 * FD * FD) return;
  int layer = t >> 14;           // FD*FD = 16384
  int i = t & (FD * FD - 1);
  const float* W = (layer == 0) ? W0 : ((layer == 1) ? W1 : W2);
  int n = i & 127, k = i >> 7;
  unsigned int u = __float_as_uint(W[k * FD + n]);
  Wt[(size_t)layer * FD * FD + (size_t)n * FD + k] =
      (ushort_t)((u + 0x7fffu + ((u >> 16) & 1u)) >> 16);
}

// ---------------- MFMA GEMM: h = x @ W (bf16), fused attention-logit epilogue ----------------
// 4 waves/block; wave computes 16 rows x 128 cols via 8 col-tiles of 16x16x32.
template <int H, bool BFIN>
__global__ __launch_bounds__(256) void gemm_mfma(const void* __restrict__ xin,
                                                 const ushort_t* __restrict__ Wt,
                                                 const float* __restrict__ as_,
                                                 const float* __restrict__ ad_,
                                                 uint_t* __restrict__ hq,
                                                 float* __restrict__ als,
                                                 float* __restrict__ ald) {
  const int l = threadIdx.x & 63;
  const int wv = threadIdx.x >> 6;
  const int n0 = blockIdx.x * 64 + wv * 16;
  const int r = l & 15;          // A-row / B-col within tile
  const int kb = l >> 4;         // k-block (8 elems each)
  const int nr = min(n0 + r, NN - 1);   // clamped A row (results for pad rows discarded)

  f32x4 acc[8];
  #pragma unroll
  for (int ct = 0; ct < 8; ++ct)
    #pragma unroll
    for (int j = 0; j < 4; ++j) acc[ct][j] = 0.f;

  #pragma unroll
  for (int kt = 0; kt < 4; ++kt) {
    bf16x8 af;
    if (BFIN) {
      af = *reinterpret_cast<const bf16x8*>(
          (const ushort_t*)xin + (size_t)nr * FD + kt * 32 + kb * 8);
    } else {
      const float* xf = (const float*)xin + (size_t)nr * FD + kt * 32 + kb * 8;
      float4 f0 = *reinterpret_cast<const float4*>(xf);
      float4 f1 = *reinterpret_cast<const float4*>(xf + 4);
      union { bf16x8 v; unsigned int u[4]; } cvt;
      cvt.u[0] = pack_bf2(f0.x, f0.y);
      cvt.u[1] = pack_bf2(f0.z, f0.w);
      cvt.u[2] = pack_bf2(f1.x, f1.y);
      cvt.u[3] = pack_bf2(f1.z, f1.w);
      af = cvt.v;
    }
    #pragma unroll
    for (int ct = 0; ct < 8; ++ct) {
      bf16x8 bf = *reinterpret_cast<const bf16x8*>(
          &Wt[(size_t)(ct * 16 + r) * FD + kt * 32 + kb * 8]);
      acc[ct] = __builtin_amdgcn_mfma_f32_16x16x32_bf16(af, bf, acc[ct], 0, 0, 0);
    }
  }

  // ---- h store (packed bf16 pairs) ----
  // C layout: row=(l>>4)*4+j, col=ct*16+(l&15)
  #pragma unroll
  for (int ct = 0; ct < 8; ++ct)
    #pragma unroll
    for (int j = 0; j < 4; ++j) {
      float v = acc[ct][j];
      float p = __shfl_xor(v, 1, 64);
      if (!(l & 1)) {
        int n = n0 + (l >> 4) * 4 + j;
        if (n < NN) hq[(size_t)n * (FD / 2) + ct * 8 + (r >> 1)] = pack_bf2(v, p);
      }
    }

  // ---- fused attention logits ----
  if (H == 4) {
    float ps[4][4], pd[4][4];
    #pragma unroll
    for (int j = 0; j < 4; ++j)
      #pragma unroll
      for (int hd = 0; hd < 4; ++hd) { ps[j][hd] = 0.f; pd[j][hd] = 0.f; }
    #pragma unroll
    for (int ct = 0; ct < 8; ++ct) {
      float a_s = as_[ct * 16 + r];
      float a_d = ad_[ct * 16 + r];
      int hd = ct >> 1;
      #pragma unroll
      for (int j = 0; j < 4; ++j) {
        ps[j][hd] = fmaf(acc[ct][j], a_s, ps[j][hd]);
        pd[j][hd] = fmaf(acc[ct][j], a_d, pd[j][hd]);
      }
    }
    #pragma unroll
    for (int off = 1; off < 16; off <<= 1)
      #pragma unroll
      for (int j = 0; j < 4; ++j)
        #pragma unroll
        for (int hd = 0; hd < 4; ++hd) {
          ps[j][hd] += __shfl_xor(ps[j][hd], off, 64);
          pd[j][hd] += __shfl_xor(pd[j][hd], off, 64);
        }
    if (r == 0) {
      #pragma unroll
      for (int j = 0; j < 4; ++j) {
        int n = n0 + (l >> 4) * 4 + j;
        if (n < NN) {
          *reinterpret_cast<float4*>(&als[n * 4]) =
              make_float4(ps[j][0], ps[j][1], ps[j][2], ps[j][3]);
          *reinterpret_cast<float4*>(&ald[n * 4]) =
              make_float4(pd[j][0], pd[j][1], pd[j][2], pd[j][3]);
        }
      }
    }
  } else {
    float ps[4], pd[4];
    #pragma unroll
    for (int j = 0; j < 4; ++j) { ps[j] = 0.f; pd[j] = 0.f; }
    #pragma unroll
    for (int ct = 0; ct < 8; ++ct) {
      float a_s = as_[ct * 16 + r];
      float a_d = ad_[ct * 16 + r];
      #pragma unroll
      for (int j = 0; j < 4; ++j) {
        ps[j] = fmaf(acc[ct][j], a_s, ps[j]);
        pd[j] = fmaf(acc[ct][j], a_d, pd[j]);
      }
    }
    #pragma unroll
    for (int off = 1; off < 16; off <<= 1)
      #pragma unroll
      for (int j = 0; j < 4; ++j) {
        ps[j] += __shfl_xor(ps[j], off, 64);
        pd[j] += __shfl_xor(pd[j], off, 64);
      }
    if (r == 0) {
      #pragma unroll
      for (int j = 0; j < 4; ++j) {
        int n = n0 + (l >> 4) * 4 + j;
        if (n < NN) { als[n] = ps[j]; ald[n] = pd[j]; }
      }
    }
  }
}

// ---------------- CSR build ----------------
__global__ __launch_bounds__(256) void zero_cnt(int* __restrict__ cnt) {
  int t = blockIdx.x * 256 + threadIdx.x;
  if (t < NN) cnt[t] = 0;
}

__global__ __launch_bounds__(256) void hist_dst(const int* __restrict__ dst,
                                                int* __restrict__ cnt) {
  int e = blockIdx.x * 256 + threadIdx.x;
  if (e < NE) atomicAdd(&cnt[dst[e]], 1);
}

__global__ __launch_bounds__(256) void block_sum(const int* __restrict__ cnt,
                                                 int* __restrict__ bsum) {
  __shared__ int red[256];
  int i = blockIdx.x * 256 + threadIdx.x;
  red[threadIdx.x] = (i < NN) ? cnt[i] : 0;
  __syncthreads();
  for (int s = 128; s > 0; s >>= 1) {
    if (threadIdx.x < s) red[threadIdx.x] += red[threadIdx.x + s];
    __syncthreads();
  }
  if (threadIdx.x == 0) bsum[blockIdx.x] = red[0];
}

__global__ __launch_bounds__(256) void scan_bsum(int* __restrict__ bsum,
                                                 int* __restrict__ row_ptr) {
  __shared__ int sh[256];
  int t = threadIdx.x;
  int v = (t < NBLK) ? bsum[t] : 0;
  sh[t] = v;
  __syncthreads();
  #pragma unroll
  for (int off = 1; off < 256; off <<= 1) {
    int u = (t >= off) ? sh[t - off] : 0;
    __syncthreads();
    sh[t] += u;
    __syncthreads();
  }
  if (t < NBLK) bsum[t] = (t == 0) ? 0 : sh[t - 1];
  if (t == 0) row_ptr[NN] = sh[NBLK - 1];
}

__global__ __launch_bounds__(256) void write_rowptr(const int* __restrict__ cnt,
                                                    const int* __restrict__ bsum,
                                                    int* __restrict__ row_ptr,
                                                    int* __restrict__ cursor) {
  __shared__ int sh[256];
  int t = threadIdx.x;
  int i = blockIdx.x * 256 + t;
  int v = (i < NN) ? cnt[i] : 0;
  sh[t] = v;
  __syncthreads();
  #pragma unroll
  for (int off = 1; off < 256; off <<= 1) {
    int u = (t >= off) ? sh[t - off] : 0;
    __syncthreads();
    sh[t] += u;
    __syncthreads();
  }
  int excl = sh[t] - v + bsum[blockIdx.x];
  if (i < NN) {
    row_ptr[i] = excl;
    cursor[i] = excl;
  }
}

__global__ __launch_bounds__(256) void scatter_edges(const int* __restrict__ src,
                                                     const int* __restrict__ dst,
                                                     int* __restrict__ cursor,
                                                     int* __restrict__ col) {
  int e = blockIdx.x * 256 + threadIdx.x;
  if (e >= NE) return;
  int pos = atomicAdd(&cursor[dst[e]], 1);
  col[pos] = src[e];
}

// ---------------- fused gather: softmax aggregation + bias + BN + ReLU ----------------
// One 64-lane wave per dst node; lane owns 2 channels (one packed bf16 pair).
// Full 16-edge chunks use a fully-unrolled register-prefetch path (16 loads in flight).
template <int H, int C>
__global__ __launch_bounds__(256) void gat_gather(const int* __restrict__ row_ptr,
                                                  const int* __restrict__ col,
                                                  const uint_t* __restrict__ hq,
                                                  const float* __restrict__ als,
                                                  const float* __restrict__ ald,
                                                  const float* __restrict__ b,
                                                  const float* __restrict__ g,
                                                  const float* __restrict__ bb,
                                                  const float* __restrict__ rm,
                                                  const float* __restrict__ rv,
                                                  uint_t* __restrict__ xq) {
  int d = (blockIdx.x * 256 + threadIdx.x) >> 6;
  if (d >= NN) return;
  const int lane = threadIdx.x & 63;
  const int j0 = lane * 2;
  const int oh = j0 / C;                 // own head (H=4: lane>>4; H=1: 0)

  const float aldo = ald[d * H + oh];
  const float wself = __expf(lrelu(als[d * H + oh] + aldo));
  uint_t hu = hq[(size_t)d * (FD / 2) + lane];
  float accx = wself * bf_lo(hu), accy = wself * bf_hi(hu);
  float dpart = 0.f;

  const int e0 = row_ptr[d], e1 = row_ptr[d + 1];
  constexpr int CH = (H == 4) ? 16 : 64;
  const int wsrc = (H == 4) ? (lane & 48) : 0;   // shfl base for own-head weights
  for (int base = e0; base < e1; base += CH) {
    int m = e1 - base;
    if (m > CH) m = CH;
    const int eidx = (H == 4) ? (lane & 15) : lane;
    int sl = 0;
    float w = 0.f;
    if (eidx < m) {
      sl = col[base + eidx];
      w = __expf(lrelu(als[sl * H + oh] + aldo));
    }
    dpart += w;
    // phase 2 in 16-edge sub-batches; full batches take the unrolled prefetch path
    for (int kb2 = 0; kb2 < m; kb2 += 16) {
      int kk = m - kb2;
      if (kk >= 16) {
        uint_t hsv[16];
        #pragma unroll
        for (int k = 0; k < 16; ++k) {
          int sk = __shfl(sl, kb2 + k, 64);
          hsv[k] = hq[(size_t)sk * (FD / 2) + lane];
        }
        #pragma unroll
        for (int k = 0; k < 16; ++k) {
          float wk = __shfl(w, wsrc + kb2 + k, 64);
          accx = fmaf(wk, bf_lo(hsv[k]), accx);
          accy = fmaf(wk, bf_hi(hsv[k]), accy);
        }
      } else {
        for (int k = 0; k < kk; ++k) {
          int sk = __shfl(sl, kb2 + k, 64);
          float wk = __shfl(w, wsrc + kb2 + k, 64);
          uint_t hs = hq[(size_t)sk * (FD / 2) + lane];
          accx = fmaf(wk, bf_lo(hs), accx);
          accy = fmaf(wk, bf_hi(hs), accy);
        }
      }
    }
  }
  // reduce edge-denominator partials within head group
  #pragma unroll
  for (int off = 1; off < ((H == 4) ? 16 : 64); off <<= 1)
    dpart += __shfl_xor(dpart, off, 64);
  float denom = dpart + wself;

  float inv = 1.f / denom;
  int j = j0;
  float v0 = accx * inv + b[j];
  float v1 = accy * inv + b[j + 1];
  v0 = g[j] * (v0 - rm[j]) * rsqrtf(rv[j] + EPS_BN) + bb[j];
  v1 = g[j + 1] * (v1 - rm[j + 1]) * rsqrtf(rv[j + 1] + EPS_BN) + bb[j + 1];
  v0 = v0 > 0.f ? v0 : 0.f;
  v1 = v1 > 0.f ? v1 : 0.f;
  xq[(size_t)d * (FD / 2) + lane] = pack_bf2(v0, v1);
}

// ---------------- pooling ----------------
__global__ __launch_bounds__(256) void pool_zero(float* __restrict__ pooled) {
  int t = blockIdx.x * 256 + threadIdx.x;
  if (t < NG * FD) pooled[t] = 0.f;
}

__global__ __launch_bounds__(128) void pool_sum(const ushort_t* __restrict__ xb,
                                                const int* __restrict__ batch,
                                                float* __restrict__ pooled) {
  int j = threadIdx.x;
  int base = blockIdx.x * 128;
  if (base >= NN) return;
  int end = base + 128;
  if (end > NN) end = NN;
  float acc = 0.f;
  int cur = batch[base];
  for (int n = base; n < end; ++n) {
    int gg = batch[n];
    if (gg != cur) {
      atomicAdd(&pooled[cur * FD + j], acc);
      acc = 0.f;
      cur = gg;
    }
    acc += bf_us(xb[(size_t)n * FD + j]);
  }
  atomicAdd(&pooled[cur * FD + j], acc);
}

// ---------------- classifier ----------------
__global__ __launch_bounds__(640) void cls_kernel(const float* __restrict__ pooled,
                                                  const float* __restrict__ Wc,
                                                  const float* __restrict__ bc,
                                                  float* __restrict__ out) {
  int t = threadIdx.x;
  if (t >= NG * NCLS_) return;
  int g = t / NCLS_, k = t % NCLS_;
  float acc = bc[k];
  #pragma unroll 16
  for (int j = 0; j < FD; ++j)
    acc = fmaf(pooled[g * FD + j], Wc[j * NCLS_ + k], acc);
  out[t] = acc;
}

extern "C" void kernel_launch(void* const* d_in, const int* in_sizes, int n_in,
                              void* d_out, int out_size, void* d_ws, size_t ws_size,
                              hipStream_t stream) {
  const float* x = (const float*)d_in[0];
  const int* ei = (const int*)d_in[1];
  const int* batch = (const int*)d_in[2];
  const int* src = ei;
  const int* dst = ei + NE;
  const float* W[3]  = {(const float*)d_in[3],  (const float*)d_in[11], (const float*)d_in[19]};
  const float* AS[3] = {(const float*)d_in[4],  (const float*)d_in[12], (const float*)d_in[20]};
  const float* AD[3] = {(const float*)d_in[5],  (const float*)d_in[13], (const float*)d_in[21]};
  const float* B[3]  = {(const float*)d_in[6],  (const float*)d_in[14], (const float*)d_in[22]};
  const float* Gm[3] = {(const float*)d_in[7],  (const float*)d_in[15], (const float*)d_in[23]};
  const float* BB[3] = {(const float*)d_in[8],  (const float*)d_in[16], (const float*)d_in[24]};
  const float* RM[3] = {(const float*)d_in[9],  (const float*)d_in[17], (const float*)d_in[25]};
  const float* RV[3] = {(const float*)d_in[10], (const float*)d_in[18], (const float*)d_in[26]};
  const float* Wc = (const float*)d_in[27];
  const float* bc = (const float*)d_in[28];

  uint_t* hq    = (uint_t*)d_ws;                          // NN_PAD*64
  uint_t* xq    = hq + (size_t)NN_PAD * (FD / 2);         // NN_PAD*64
  float* als    = (float*)(xq + (size_t)NN_PAD * (FD / 2)); // NN*4
  float* ald    = als + (size_t)NN * 4;                   // NN*4
  float* pooled = ald + (size_t)NN * 4;                   // NG*FD
  ushort_t* Wt  = (ushort_t*)(pooled + (size_t)NG * FD);  // 3*128*128 bf16
  int* cnt      = (int*)(Wt + (size_t)3 * FD * FD);       // NN
  int* row_ptr  = cnt + NN;                               // NN+1
  int* cursor   = row_ptr + NN + 1;                       // NN
  int* col      = cursor + NN;                            // NE
  int* bsum     = col + NE;                               // NBLK

  // ---- weight pack (all layers) + CSR by destination (shared by all 3 layers) ----
  wt_pack3<<<(3 * FD * FD + 255) / 256, 256, 0, stream>>>(W[0], W[1], W[2], Wt);
  zero_cnt<<<NBLK, 256, 0, stream>>>(cnt);
  hist_dst<<<(NE + 255) / 256, 256, 0, stream>>>(dst, cnt);
  block_sum<<<NBLK, 256, 0, stream>>>(cnt, bsum);
  scan_bsum<<<1, 256, 0, stream>>>(bsum, row_ptr);
  write_rowptr<<<NBLK, 256, 0, stream>>>(cnt, bsum, row_ptr, cursor);
  scatter_edges<<<(NE + 255) / 256, 256, 0, stream>>>(src, dst, cursor, col);

  const int gemm_blocks = NN_PAD / 64;     // 782
  const int gather_blocks = (NN + 3) / 4;

  // layer 0 (fp32 input)
  gemm_mfma<4, false><<<gemm_blocks, 256, 0, stream>>>(x, Wt, AS[0], AD[0], hq, als, ald);
  gat_gather<4, 32><<<gather_blocks, 256, 0, stream>>>(row_ptr, col, hq, als, ald,
      B[0], Gm[0], BB[0], RM[0], RV[0], xq);
  // layer 1 (bf16 input)
  gemm_mfma<4, true><<<gemm_blocks, 256, 0, stream>>>(xq, Wt + (size_t)FD * FD, AS[1], AD[1], hq, als, ald);
  gat_gather<4, 32><<<gather_blocks, 256, 0, stream>>>(row_ptr, col, hq, als, ald,
      B[1], Gm[1], BB[1], RM[1], RV[1], xq);
  // layer 2 (bf16 input, single head)
  gemm_mfma<1, true><<<gemm_blocks, 256, 0, stream>>>(xq, Wt + (size_t)2 * FD * FD, AS[2], AD[2], hq, als, ald);
  gat_gather<1, 128><<<gather_blocks, 256, 0, stream>>>(row_ptr, col, hq, als, ald,
      B[2], Gm[2], BB[2], RM[2], RV[2], xq);

  pool_zero<<<(NG * FD + 255) / 256, 256, 0, stream>>>(pooled);
  pool_sum<<<(NN + 127) / 128, 128, 0, stream>>>((const ushort_t*)xq, batch, pooled);
  cls_kernel<<<1, 640, 0, stream>>>(pooled, Wc, bc, (float*)d_out);
}